// Round 1
// baseline (398.572 us; speedup 1.0000x reference)
//
#include <hip/hip_runtime.h>
#include <hip/hip_bf16.h>

#define ALPHA 2.0f
#define BETA 50.0f
#define BASE 0.5f
#define MARGIN 0.1f

constexpr int NB = 8192;   // batch
constexpr int ND = 1024;   // dim

typedef __attribute__((ext_vector_type(8))) short bf16x8;
typedef __attribute__((ext_vector_type(4))) float f32x4;

#define GLOAD_LDS16(g, l) \
  __builtin_amdgcn_global_load_lds((const __attribute__((address_space(1))) void*)(g), \
                                   (__attribute__((address_space(3))) void*)(l), 16, 0, 0)

static __device__ inline unsigned short f2bf(float x) {
  // round-to-nearest-even bf16 (finite inputs)
  unsigned int u = __float_as_uint(x);
  unsigned int r = u + 0x7FFFu + ((u >> 16) & 1u);
  return (unsigned short)(r >> 16);
}

// --------------------------------------------------------------------------
// K1: row-normalize f1,f2 -> bf16; diag[i] = dot(f1n_i, f2n_i) in fp32
__global__ __launch_bounds__(256) void norm_diag_kernel(
    const float* __restrict__ f1, const float* __restrict__ f2,
    unsigned short* __restrict__ f1n, unsigned short* __restrict__ f2n,
    float* __restrict__ diag)
{
  const int row = blockIdx.x;
  const int tid = threadIdx.x;
  const float4* r1 = (const float4*)(f1 + (size_t)row * ND);
  const float4* r2 = (const float4*)(f2 + (size_t)row * ND);
  float4 a = r1[tid];
  float4 b = r2[tid];
  float ss1 = a.x*a.x + a.y*a.y + a.z*a.z + a.w*a.w;
  float ss2 = b.x*b.x + b.y*b.y + b.z*b.z + b.w*b.w;
  float d12 = a.x*b.x + a.y*b.y + a.z*b.z + a.w*b.w;
  #pragma unroll
  for (int m = 1; m < 64; m <<= 1) {
    ss1 += __shfl_xor(ss1, m);
    ss2 += __shfl_xor(ss2, m);
    d12 += __shfl_xor(d12, m);
  }
  __shared__ float red[3][4];
  const int wid = tid >> 6, lane = tid & 63;
  if (lane == 0) { red[0][wid] = ss1; red[1][wid] = ss2; red[2][wid] = d12; }
  __syncthreads();
  ss1 = red[0][0] + red[0][1] + red[0][2] + red[0][3];
  ss2 = red[1][0] + red[1][1] + red[1][2] + red[1][3];
  d12 = red[2][0] + red[2][1] + red[2][2] + red[2][3];
  const float rn1 = rsqrtf(ss1);
  const float rn2 = rsqrtf(ss2);
  if (tid == 0) diag[row] = d12 * rn1 * rn2;
  ushort4 o1, o2;
  o1.x = f2bf(a.x * rn1); o1.y = f2bf(a.y * rn1);
  o1.z = f2bf(a.z * rn1); o1.w = f2bf(a.w * rn1);
  o2.x = f2bf(b.x * rn2); o2.y = f2bf(b.y * rn2);
  o2.z = f2bf(b.z * rn2); o2.w = f2bf(b.w * rn2);
  ((ushort4*)f1n)[(size_t)row * 256 + tid] = o1;
  ((ushort4*)f2n)[(size_t)row * 256 + tid] = o2;
}

// --------------------------------------------------------------------------
// K2: 128x128-tile bf16 MFMA "GEMM" with fused MS-loss epilogue.
//   sim tile never hits memory; epilogue accumulates masked exp sums into
//   row_sum / col_sum via wave shuffle reduce + atomicAdd.
__global__ __launch_bounds__(256) void simloss_gemm_kernel(
    const unsigned short* __restrict__ f1n, const unsigned short* __restrict__ f2n,
    const float* __restrict__ diag,
    float* __restrict__ row_sum, float* __restrict__ col_sum)
{
  __shared__ __align__(16) unsigned short Als[128 * 64];
  __shared__ __align__(16) unsigned short Bls[128 * 64];
  __shared__ float drow[128];
  __shared__ float dcol[128];

  const int tid  = threadIdx.x;
  const int lane = tid & 63;
  const int wid  = tid >> 6;
  const int wm   = wid >> 1;   // wave row 0..1
  const int wn   = wid & 1;    // wave col 0..1
  const int brow = blockIdx.y * 128;
  const int bcol = blockIdx.x * 128;

  if (tid < 128) drow[tid] = diag[brow + tid];
  else           dcol[tid - 128] = diag[bcol + tid - 128];

  f32x4 acc[4][4];
  #pragma unroll
  for (int m = 0; m < 4; m++)
    #pragma unroll
    for (int n = 0; n < 4; n++)
      acc[m][n] = (f32x4){0.f, 0.f, 0.f, 0.f};

  const int srow = lane >> 3;          // 0..7 within chunk
  const int scol = (lane & 7) * 8;     // k offset of this lane's 16B

  for (int k0 = 0; k0 < ND; k0 += 64) {
    #pragma unroll
    for (int t = 0; t < 4; ++t) {
      const int c = wid * 4 + t;                 // chunk 0..15, wave-uniform
      const int arow = c * 8 + srow;             // tile row 0..127
      const unsigned short* gA = f1n + (size_t)(brow + arow) * ND + k0 + scol;
      const unsigned short* gB = f2n + (size_t)(bcol + arow) * ND + k0 + scol;
      GLOAD_LDS16(gA, Als + c * 512);
      GLOAD_LDS16(gB, Bls + c * 512);
    }
    __syncthreads();
    #pragma unroll
    for (int kk = 0; kk < 2; ++kk) {
      const int kb = kk * 32 + (lane >> 4) * 8;
      bf16x8 af[4], bfr[4];
      #pragma unroll
      for (int m = 0; m < 4; m++) {
        const int rt = wm * 64 + m * 16 + (lane & 15);
        af[m] = *(const bf16x8*)&Als[rt * 64 + kb];
      }
      #pragma unroll
      for (int n = 0; n < 4; n++) {
        const int rt = wn * 64 + n * 16 + (lane & 15);
        bfr[n] = *(const bf16x8*)&Bls[rt * 64 + kb];
      }
      #pragma unroll
      for (int m = 0; m < 4; m++)
        #pragma unroll
        for (int n = 0; n < 4; n++)
          acc[m][n] = __builtin_amdgcn_mfma_f32_16x16x32_bf16(af[m], bfr[n], acc[m][n], 0, 0, 0);
    }
    __syncthreads();
  }

  // ---- epilogue: masked exp accumulation ----
  const int cgrp = lane >> 4;   // 0..3
  const int c15  = lane & 15;
  float rp[4][4];               // per (m, reg) row partials (summed over n)
  float cp[4];                  // per n col partials (summed over m, reg)
  #pragma unroll
  for (int m = 0; m < 4; m++)
    #pragma unroll
    for (int r = 0; r < 4; r++) rp[m][r] = 0.f;
  #pragma unroll
  for (int n = 0; n < 4; n++) cp[n] = 0.f;

  #pragma unroll
  for (int n = 0; n < 4; n++) {
    const int ct   = wn * 64 + n * 16 + c15;   // tile col
    const int gcol = bcol + ct;
    const float dc = dcol[ct];
    #pragma unroll
    for (int m = 0; m < 4; m++) {
      #pragma unroll
      for (int r = 0; r < 4; r++) {
        const int rt   = wm * 64 + m * 16 + cgrp * 4 + r;
        const int grow = brow + rt;
        const float s  = acc[m][n][r];
        const float e  = __expf(BETA * (s - BASE));
        const float dr = drow[rt];
        const bool off = (grow != gcol);
        if (off && (s + MARGIN > dr)) rp[m][r] += e;
        if (off && (s + MARGIN > dc)) cp[n] += e;
      }
    }
  }
  // row sums: reduce across the 16 lanes sharing a row (vary c15)
  #pragma unroll
  for (int m = 0; m < 4; m++) {
    #pragma unroll
    for (int r = 0; r < 4; r++) {
      float v = rp[m][r];
      v += __shfl_xor(v, 1); v += __shfl_xor(v, 2);
      v += __shfl_xor(v, 4); v += __shfl_xor(v, 8);
      if (c15 == 0) {
        const int rt = wm * 64 + m * 16 + cgrp * 4 + r;
        atomicAdd(&row_sum[brow + rt], v);
      }
    }
  }
  // col sums: reduce across the 4 lane-groups sharing a col (vary cgrp)
  #pragma unroll
  for (int n = 0; n < 4; n++) {
    float v = cp[n];
    v += __shfl_xor(v, 16); v += __shfl_xor(v, 32);
    if (cgrp == 0) {
      const int ct = wn * 64 + n * 16 + c15;
      atomicAdd(&col_sum[bcol + ct], v);
    }
  }
}

// --------------------------------------------------------------------------
// K3: final scalar reduction
__global__ __launch_bounds__(256) void finalize_kernel(
    const float* __restrict__ diag, const float* __restrict__ row_sum,
    const float* __restrict__ col_sum, float* __restrict__ out)
{
  const int tid = threadIdx.x;
  float sp = 0.f, sr = 0.f, sc = 0.f;
  for (int i = tid; i < NB; i += 256) {
    const float pos = diag[i];
    const float x = -ALPHA * (pos - BASE);
    // stable softplus(x) = max(x,0) + log1p(exp(-|x|))
    sp += (fmaxf(x, 0.f) + log1pf(__expf(-fabsf(x)))) / ALPHA;
    sr += log1pf(row_sum[i]);
    sc += log1pf(col_sum[i]);
  }
  #pragma unroll
  for (int m = 1; m < 64; m <<= 1) {
    sp += __shfl_xor(sp, m);
    sr += __shfl_xor(sr, m);
    sc += __shfl_xor(sc, m);
  }
  __shared__ float red[3][4];
  const int wid = tid >> 6, lane = tid & 63;
  if (lane == 0) { red[0][wid] = sp; red[1][wid] = sr; red[2][wid] = sc; }
  __syncthreads();
  if (tid == 0) {
    sp = red[0][0] + red[0][1] + red[0][2] + red[0][3];
    sr = red[1][0] + red[1][1] + red[1][2] + red[1][3];
    sc = red[2][0] + red[2][1] + red[2][2] + red[2][3];
    out[0] = sp / (float)NB + (sr + sc) / (2.f * BETA * (float)NB);
  }
}

// --------------------------------------------------------------------------
extern "C" void kernel_launch(void* const* d_in, const int* in_sizes, int n_in,
                              void* d_out, int out_size, void* d_ws, size_t ws_size,
                              hipStream_t stream) {
  const float* f1 = (const float*)d_in[0];
  const float* f2 = (const float*)d_in[1];
  float* out = (float*)d_out;

  char* ws = (char*)d_ws;
  unsigned short* f1n = (unsigned short*)ws;                          // 16 MB
  unsigned short* f2n = (unsigned short*)(ws + (size_t)16 * 1024 * 1024); // 16 MB
  float* diag    = (float*)(ws + (size_t)32 * 1024 * 1024);           // 32 KB
  float* row_sum = diag + NB;                                         // 32 KB
  float* col_sum = row_sum + NB;                                      // 32 KB

  hipMemsetAsync(row_sum, 0, 2 * NB * sizeof(float), stream);

  norm_diag_kernel<<<NB, 256, 0, stream>>>(f1, f2, f1n, f2n, diag);

  dim3 grid(NB / 128, NB / 128);
  simloss_gemm_kernel<<<grid, 256, 0, stream>>>(f1n, f2n, diag, row_sum, col_sum);

  finalize_kernel<<<1, 256, 0, stream>>>(diag, row_sum, col_sum, out);
}

// Round 2
// 374.733 us; speedup vs baseline: 1.0636x; 1.0636x over previous
//
#include <hip/hip_runtime.h>
#include <hip/hip_bf16.h>

#define ALPHA 2.0f
#define BETA 50.0f
#define BASE 0.5f
#define MARGIN 0.1f

constexpr int NB = 8192;   // batch
constexpr int ND = 1024;   // dim

typedef __attribute__((ext_vector_type(8))) short bf16x8;
typedef __attribute__((ext_vector_type(4))) float f32x4;

#define GLOAD_LDS16(g, l) \
  __builtin_amdgcn_global_load_lds((const __attribute__((address_space(1))) void*)(g), \
                                   (__attribute__((address_space(3))) void*)(l), 16, 0, 0)

static __device__ inline unsigned short f2bf(float x) {
  // round-to-nearest-even bf16 (finite inputs)
  unsigned int u = __float_as_uint(x);
  unsigned int r = u + 0x7FFFu + ((u >> 16) & 1u);
  return (unsigned short)(r >> 16);
}

// --------------------------------------------------------------------------
// K1: row-normalize f1,f2 -> bf16; diag[i] = dot(f1n_i, f2n_i) in fp32.
// Also zeroes row_sum/col_sum (harness re-poisons ws each call).
__global__ __launch_bounds__(256) void norm_diag_kernel(
    const float* __restrict__ f1, const float* __restrict__ f2,
    unsigned short* __restrict__ f1n, unsigned short* __restrict__ f2n,
    float* __restrict__ diag, float* __restrict__ row_sum,
    float* __restrict__ col_sum)
{
  const int row = blockIdx.x;
  const int tid = threadIdx.x;
  const float4* r1 = (const float4*)(f1 + (size_t)row * ND);
  const float4* r2 = (const float4*)(f2 + (size_t)row * ND);
  float4 a = r1[tid];
  float4 b = r2[tid];
  float ss1 = a.x*a.x + a.y*a.y + a.z*a.z + a.w*a.w;
  float ss2 = b.x*b.x + b.y*b.y + b.z*b.z + b.w*b.w;
  float d12 = a.x*b.x + a.y*b.y + a.z*b.z + a.w*b.w;
  #pragma unroll
  for (int m = 1; m < 64; m <<= 1) {
    ss1 += __shfl_xor(ss1, m);
    ss2 += __shfl_xor(ss2, m);
    d12 += __shfl_xor(d12, m);
  }
  __shared__ float red[3][4];
  const int wid = tid >> 6, lane = tid & 63;
  if (lane == 0) { red[0][wid] = ss1; red[1][wid] = ss2; red[2][wid] = d12; }
  __syncthreads();
  ss1 = red[0][0] + red[0][1] + red[0][2] + red[0][3];
  ss2 = red[1][0] + red[1][1] + red[1][2] + red[1][3];
  d12 = red[2][0] + red[2][1] + red[2][2] + red[2][3];
  const float rn1 = rsqrtf(ss1);
  const float rn2 = rsqrtf(ss2);
  if (tid == 0) diag[row] = d12 * rn1 * rn2;
  if (tid == 1) row_sum[row] = 0.f;
  if (tid == 2) col_sum[row] = 0.f;
  ushort4 o1, o2;
  o1.x = f2bf(a.x * rn1); o1.y = f2bf(a.y * rn1);
  o1.z = f2bf(a.z * rn1); o1.w = f2bf(a.w * rn1);
  o2.x = f2bf(b.x * rn2); o2.y = f2bf(b.y * rn2);
  o2.z = f2bf(b.z * rn2); o2.w = f2bf(b.w * rn2);
  ((ushort4*)f1n)[(size_t)row * 256 + tid] = o1;
  ((ushort4*)f2n)[(size_t)row * 256 + tid] = o2;
}

// --------------------------------------------------------------------------
// K2: 128x128-tile bf16 MFMA "GEMM" with fused MS-loss epilogue.
// LDS layout carries a T2 XOR swizzle: 16B chunk j of row r lives at
// byte (r*128 + ((j ^ (r&7))<<4)). Achieved with LINEAR global_load_lds
// dest + pre-swizzled GLOBAL source (rule #21 / m173), un-swizzled on read.
__global__ __launch_bounds__(256) void simloss_gemm_kernel(
    const unsigned short* __restrict__ f1n, const unsigned short* __restrict__ f2n,
    const float* __restrict__ diag,
    float* __restrict__ row_sum, float* __restrict__ col_sum)
{
  __shared__ __align__(16) unsigned short Als[128 * 64];
  __shared__ __align__(16) unsigned short Bls[128 * 64];
  __shared__ float drow[128];
  __shared__ float dcol[128];

  const int tid  = threadIdx.x;
  const int lane = tid & 63;
  const int wid  = tid >> 6;
  const int wm   = wid >> 1;   // wave row 0..1
  const int wn   = wid & 1;    // wave col 0..1
  const int brow = blockIdx.y * 128;
  const int bcol = blockIdx.x * 128;

  if (tid < 128) drow[tid] = diag[brow + tid];
  else           dcol[tid - 128] = diag[bcol + tid - 128];

  f32x4 acc[4][4];
  #pragma unroll
  for (int m = 0; m < 4; m++)
    #pragma unroll
    for (int n = 0; n < 4; n++)
      acc[m][n] = (f32x4){0.f, 0.f, 0.f, 0.f};

  const int srow = lane >> 3;          // row 0..7 within chunk
  const int jsw  = (lane & 7) ^ srow;  // pre-swizzled source 16B-chunk index

  for (int k0 = 0; k0 < ND; k0 += 64) {
    #pragma unroll
    for (int t = 0; t < 4; ++t) {
      const int c = wid * 4 + t;                 // chunk 0..15, wave-uniform
      const int arow = c * 8 + srow;             // tile row 0..127
      const unsigned short* gA = f1n + (size_t)(brow + arow) * ND + k0 + jsw * 8;
      const unsigned short* gB = f2n + (size_t)(bcol + arow) * ND + k0 + jsw * 8;
      GLOAD_LDS16(gA, Als + c * 512);
      GLOAD_LDS16(gB, Bls + c * 512);
    }
    __syncthreads();
    #pragma unroll
    for (int kk = 0; kk < 2; ++kk) {
      const int jk = kk * 4 + (lane >> 4);       // 16B chunk along K (0..7)
      bf16x8 af[4], bfr[4];
      #pragma unroll
      for (int m = 0; m < 4; m++) {
        const int rt = wm * 64 + m * 16 + (lane & 15);
        af[m] = *(const bf16x8*)&Als[rt * 64 + ((jk ^ (rt & 7)) << 3)];
      }
      #pragma unroll
      for (int n = 0; n < 4; n++) {
        const int rt = wn * 64 + n * 16 + (lane & 15);
        bfr[n] = *(const bf16x8*)&Bls[rt * 64 + ((jk ^ (rt & 7)) << 3)];
      }
      #pragma unroll
      for (int m = 0; m < 4; m++)
        #pragma unroll
        for (int n = 0; n < 4; n++)
          acc[m][n] = __builtin_amdgcn_mfma_f32_16x16x32_bf16(af[m], bfr[n], acc[m][n], 0, 0, 0);
    }
    __syncthreads();
  }

  // ---- epilogue: masked exp accumulation ----
  const int cgrp = lane >> 4;   // 0..3
  const int c15  = lane & 15;
  float rp[4][4];               // per (m, reg) row partials (summed over n)
  float cp[4];                  // per n col partials (summed over m, reg)
  #pragma unroll
  for (int m = 0; m < 4; m++)
    #pragma unroll
    for (int r = 0; r < 4; r++) rp[m][r] = 0.f;
  #pragma unroll
  for (int n = 0; n < 4; n++) cp[n] = 0.f;

  #pragma unroll
  for (int n = 0; n < 4; n++) {
    const int ct   = wn * 64 + n * 16 + c15;   // tile col
    const int gcol = bcol + ct;
    const float dc = dcol[ct];
    #pragma unroll
    for (int m = 0; m < 4; m++) {
      #pragma unroll
      for (int r = 0; r < 4; r++) {
        const int rt   = wm * 64 + m * 16 + cgrp * 4 + r;
        const int grow = brow + rt;
        const float s  = acc[m][n][r];
        const float e  = __expf(BETA * (s - BASE));
        const float dr = drow[rt];
        const bool off = (grow != gcol);
        if (off && (s + MARGIN > dr)) rp[m][r] += e;
        if (off && (s + MARGIN > dc)) cp[n] += e;
      }
    }
  }
  // row sums: reduce across the 16 lanes sharing a row (vary c15)
  #pragma unroll
  for (int m = 0; m < 4; m++) {
    #pragma unroll
    for (int r = 0; r < 4; r++) {
      float v = rp[m][r];
      v += __shfl_xor(v, 1); v += __shfl_xor(v, 2);
      v += __shfl_xor(v, 4); v += __shfl_xor(v, 8);
      if (c15 == 0) {
        const int rt = wm * 64 + m * 16 + cgrp * 4 + r;
        atomicAdd(&row_sum[brow + rt], v);
      }
    }
  }
  // col sums: reduce across the 4 lane-groups sharing a col (vary cgrp)
  #pragma unroll
  for (int n = 0; n < 4; n++) {
    float v = cp[n];
    v += __shfl_xor(v, 16); v += __shfl_xor(v, 32);
    if (cgrp == 0) {
      const int ct = wn * 64 + n * 16 + c15;
      atomicAdd(&col_sum[bcol + ct], v);
    }
  }
}

// --------------------------------------------------------------------------
// K3: final scalar reduction (1024 threads to cut latency-bound tail)
__global__ __launch_bounds__(1024) void finalize_kernel(
    const float* __restrict__ diag, const float* __restrict__ row_sum,
    const float* __restrict__ col_sum, float* __restrict__ out)
{
  const int tid = threadIdx.x;
  float sp = 0.f, sr = 0.f, sc = 0.f;
  for (int i = tid; i < NB; i += 1024) {
    const float pos = diag[i];
    const float x = -ALPHA * (pos - BASE);
    // stable softplus(x) = max(x,0) + log1p(exp(-|x|))
    sp += (fmaxf(x, 0.f) + log1pf(__expf(-fabsf(x)))) / ALPHA;
    sr += log1pf(row_sum[i]);
    sc += log1pf(col_sum[i]);
  }
  #pragma unroll
  for (int m = 1; m < 64; m <<= 1) {
    sp += __shfl_xor(sp, m);
    sr += __shfl_xor(sr, m);
    sc += __shfl_xor(sc, m);
  }
  __shared__ float red[3][16];
  const int wid = tid >> 6, lane = tid & 63;
  if (lane == 0) { red[0][wid] = sp; red[1][wid] = sr; red[2][wid] = sc; }
  __syncthreads();
  if (tid == 0) {
    sp = 0.f; sr = 0.f; sc = 0.f;
    #pragma unroll
    for (int w = 0; w < 16; w++) { sp += red[0][w]; sr += red[1][w]; sc += red[2][w]; }
    out[0] = sp / (float)NB + (sr + sc) / (2.f * BETA * (float)NB);
  }
}

// --------------------------------------------------------------------------
extern "C" void kernel_launch(void* const* d_in, const int* in_sizes, int n_in,
                              void* d_out, int out_size, void* d_ws, size_t ws_size,
                              hipStream_t stream) {
  const float* f1 = (const float*)d_in[0];
  const float* f2 = (const float*)d_in[1];
  float* out = (float*)d_out;

  char* ws = (char*)d_ws;
  unsigned short* f1n = (unsigned short*)ws;                          // 16 MB
  unsigned short* f2n = (unsigned short*)(ws + (size_t)16 * 1024 * 1024); // 16 MB
  float* diag    = (float*)(ws + (size_t)32 * 1024 * 1024);           // 32 KB
  float* row_sum = diag + NB;                                         // 32 KB
  float* col_sum = row_sum + NB;                                      // 32 KB

  norm_diag_kernel<<<NB, 256, 0, stream>>>(f1, f2, f1n, f2n, diag, row_sum, col_sum);

  dim3 grid(NB / 128, NB / 128);
  simloss_gemm_kernel<<<grid, 256, 0, stream>>>(f1n, f2n, diag, row_sum, col_sum);

  finalize_kernel<<<1, 1024, 0, stream>>>(diag, row_sum, col_sum, out);
}

// Round 5
// 322.033 us; speedup vs baseline: 1.2377x; 1.1636x over previous
//
#include <hip/hip_runtime.h>
#include <hip/hip_bf16.h>

#define ALPHA 2.0f
#define BETA 50.0f
#define BASE 0.5f
#define MARGIN 0.1f

constexpr int NB = 8192;   // batch
constexpr int ND = 1024;   // dim
constexpr int BK = 64;     // K-tile
constexpr int NT = ND / BK; // 16 K-tiles (power of 2 -> wrap with &15)

typedef __attribute__((ext_vector_type(8))) short bf16x8;
typedef __attribute__((ext_vector_type(4))) float f32x4;

#define GLOAD_LDS16(g, l) \
  __builtin_amdgcn_global_load_lds((const __attribute__((address_space(1))) void*)(g), \
                                   (__attribute__((address_space(3))) void*)(l), 16, 0, 0)
#define BAR()    asm volatile("s_barrier" ::: "memory")
#define WAITV4() asm volatile("s_waitcnt vmcnt(4)" ::: "memory")

static __device__ inline unsigned short f2bf(float x) {
  unsigned int u = __float_as_uint(x);
  unsigned int r = u + 0x7FFFu + ((u >> 16) & 1u);
  return (unsigned short)(r >> 16);
}

// --------------------------------------------------------------------------
// K1: row-normalize f1,f2 -> bf16; diag[i] = dot(f1n_i, f2n_i); zero sums.
__global__ __launch_bounds__(256) void norm_diag_kernel(
    const float* __restrict__ f1, const float* __restrict__ f2,
    unsigned short* __restrict__ f1n, unsigned short* __restrict__ f2n,
    float* __restrict__ diag, float* __restrict__ row_sum,
    float* __restrict__ col_sum)
{
  const int row = blockIdx.x;
  const int tid = threadIdx.x;
  const float4* r1 = (const float4*)(f1 + (size_t)row * ND);
  const float4* r2 = (const float4*)(f2 + (size_t)row * ND);
  float4 a = r1[tid];
  float4 b = r2[tid];
  float ss1 = a.x*a.x + a.y*a.y + a.z*a.z + a.w*a.w;
  float ss2 = b.x*b.x + b.y*b.y + b.z*b.z + b.w*b.w;
  float d12 = a.x*b.x + a.y*b.y + a.z*b.z + a.w*b.w;
  #pragma unroll
  for (int m = 1; m < 64; m <<= 1) {
    ss1 += __shfl_xor(ss1, m);
    ss2 += __shfl_xor(ss2, m);
    d12 += __shfl_xor(d12, m);
  }
  __shared__ float red[3][4];
  const int wid = tid >> 6, lane = tid & 63;
  if (lane == 0) { red[0][wid] = ss1; red[1][wid] = ss2; red[2][wid] = d12; }
  __syncthreads();
  ss1 = red[0][0] + red[0][1] + red[0][2] + red[0][3];
  ss2 = red[1][0] + red[1][1] + red[1][2] + red[1][3];
  d12 = red[2][0] + red[2][1] + red[2][2] + red[2][3];
  const float rn1 = rsqrtf(ss1);
  const float rn2 = rsqrtf(ss2);
  if (tid == 0) diag[row] = d12 * rn1 * rn2;
  if (tid == 1) row_sum[row] = 0.f;
  if (tid == 2) col_sum[row] = 0.f;
  ushort4 o1, o2;
  o1.x = f2bf(a.x * rn1); o1.y = f2bf(a.y * rn1);
  o1.z = f2bf(a.z * rn1); o1.w = f2bf(a.w * rn1);
  o2.x = f2bf(b.x * rn2); o2.y = f2bf(b.y * rn2);
  o2.z = f2bf(b.z * rn2); o2.w = f2bf(b.w * rn2);
  ((ushort4*)f1n)[(size_t)row * 256 + tid] = o1;
  ((ushort4*)f2n)[(size_t)row * 256 + tid] = o2;
}

// --------------------------------------------------------------------------
// K2: 256x256-tile, 8-wave, phase-scheduled bf16 MFMA GEMM with fused
// MS-loss epilogue. T2 XOR-swizzled LDS (linear global_load_lds dest +
// pre-swizzled global source + swizzled ds_read), counted vmcnt(4) once
// per K-tile (T4), raw s_barrier (no vmcnt(0) drain), setprio (T5).
//
// Region read ledger per window t (b=t&1, bn=b^1; all ds_reads from S[b]):
//   A0=S[*][0][0..8192)   read p1 (wm=0, rows 0-63)   + p3 (wm=0, rows 64-127)
//   A1=S[*][0][8192..)    read p1 (wm=1, rows128-191) + p3 (wm=1, rows192-255)
//   B0=S[*][1][0..8192)   read p1 (wn=0,1 b0 frags)   + p2 (wn=0,1 b1 frags)
//   B1=S[*][1][8192..)    read p1 (wn=2,3 b0 frags)   + p2 (wn=2,3 b1 frags)
// Stage placement (stage issue must be >=1 barrier after target's last read):
//   p1: A1(t+1)->S[bn]   (A1[bn] last read t-1 p3: >=3 BARs)  OK
//   p2: B1(t+1)->S[bn]   (B1[bn] last read t-1 p2: >=4 BARs)  OK
//   p3: B0(t+2)->S[b]    (B0(t)  last read t p2:   1 BAR)     OK
//   p4: A0(t+2)->S[b]    (A0(t)  last read t p3:   1 BAR)     OK
// Issue order A1,B1,B0,A0 => vmcnt(4) at p4 completes all of tile t+1,
// leaving the 4 loads of {B0,A0}(t+2) in flight.
__global__ __launch_bounds__(512, 2) void simloss_gemm_kernel(
    const unsigned short* __restrict__ f1n, const unsigned short* __restrict__ f2n,
    const float* __restrict__ diag,
    float* __restrict__ row_sum, float* __restrict__ col_sum)
{
  __shared__ unsigned short S[2][2][16384];  // [dbuf][A/B][256 rows x 64 cols]
  __shared__ float drow[256];
  __shared__ float dcol[256];

  const int tid  = threadIdx.x;
  const int lane = tid & 63;
  const int wid  = tid >> 6;
  const int wm   = wid >> 2;   // 0..1  -> rows [wm*128, +128)
  const int wn   = wid & 3;    // 0..3  -> cols [wn*64, +64)
  const int brow = blockIdx.y * 256;
  const int bcol = blockIdx.x * 256;

  if (tid < 256) drow[tid] = diag[brow + tid];
  else           dcol[tid - 256] = diag[bcol + tid - 256];

  // ---- staging constants (2 x 16B per thread per half-tile) ----
  // half-tile = 128 rows x 64 cols bf16; chunk cidx in [0,1024): row=cidx>>3,
  // 16B slot j=cidx&7 stored linearly, sourced from global chunk j^(row&7).
  const int c0 = tid, c1 = tid + 512;
  const size_t off0 = (size_t)(c0 >> 3) * ND + (size_t)((((c0 & 7) ^ ((c0 >> 3) & 7))) * 8);
  const size_t off1 = (size_t)(c1 >> 3) * ND + (size_t)((((c1 & 7) ^ ((c1 >> 3) & 7))) * 8);
  const int lo0 = tid * 8, lo1 = tid * 8 + 4096;  // linear LDS dest (shorts)

  const unsigned short* pA0 = f1n + (size_t)brow * ND;
  const unsigned short* pA1 = pA0 + (size_t)128 * ND;
  const unsigned short* pB0 = f2n + (size_t)bcol * ND;
  const unsigned short* pB1 = pB0 + (size_t)128 * ND;

  #define STAGE(ldsbase, g, kk) do { \
    GLOAD_LDS16((g) + off0 + (kk), (ldsbase) + lo0); \
    GLOAD_LDS16((g) + off1 + (kk), (ldsbase) + lo1); } while (0)

  f32x4 acc[8][4];
  #pragma unroll
  for (int m = 0; m < 8; m++)
    #pragma unroll
    for (int n = 0; n < 4; n++)
      acc[m][n] = (f32x4){0.f, 0.f, 0.f, 0.f};

  // ---- fragment read constants ----
  const int hi = lane >> 4, l15 = lane & 15;
  const int x7 = l15 & 7;
  const int swz0 = (hi ^ x7) * 8;        // k-chunk 0 slot (shorts offset)
  const int swz1 = ((hi + 4) ^ x7) * 8;  // k-chunk 1 slot
  const int abase = (wm * 128 + l15) * 64;
  const int bbase = (wn * 64 + l15) * 64;

  // ---- prologue: tile0 fully + A0/B0 of tile1; keep last 4 loads in flight
  STAGE(&S[0][0][0],    pA0, 0);
  STAGE(&S[0][1][0],    pB0, 0);
  STAGE(&S[0][0][8192], pA1, 0);
  STAGE(&S[0][1][8192], pB1, 0);
  STAGE(&S[1][0][0],    pA0, BK);
  STAGE(&S[1][1][0],    pB0, BK);
  WAITV4();
  BAR();

  bf16x8 a[4][2], b0[2][2], b1[2][2];

  for (int t = 0; t < NT; ++t) {
    const int b  = t & 1, bn = b ^ 1;
    const int k1 = ((t + 1) & 15) * BK;   // wraps harmlessly in last windows
    const int k2 = ((t + 2) & 15) * BK;
    const unsigned short* PA = &S[b][0][0];
    const unsigned short* PB = &S[b][1][0];

    // ---- p1: Q00 (m 0..3, n 0..1) ----
    #pragma unroll
    for (int m = 0; m < 4; ++m) {
      a[m][0] = *(const bf16x8*)&PA[abase + m * 1024 + swz0];
      a[m][1] = *(const bf16x8*)&PA[abase + m * 1024 + swz1];
    }
    #pragma unroll
    for (int n = 0; n < 2; ++n) {
      b0[n][0] = *(const bf16x8*)&PB[bbase + n * 1024 + swz0];
      b0[n][1] = *(const bf16x8*)&PB[bbase + n * 1024 + swz1];
    }
    STAGE(&S[bn][0][8192], pA1, k1);
    BAR();
    __builtin_amdgcn_s_setprio(1);
    #pragma unroll
    for (int m = 0; m < 4; ++m)
      #pragma unroll
      for (int n = 0; n < 2; ++n) {
        acc[m][n] = __builtin_amdgcn_mfma_f32_16x16x32_bf16(a[m][0], b0[n][0], acc[m][n], 0, 0, 0);
        acc[m][n] = __builtin_amdgcn_mfma_f32_16x16x32_bf16(a[m][1], b0[n][1], acc[m][n], 0, 0, 0);
      }
    __builtin_amdgcn_s_setprio(0);
    BAR();

    // ---- p2: Q01 (m 0..3, n 2..3) ----
    #pragma unroll
    for (int n = 0; n < 2; ++n) {
      b1[n][0] = *(const bf16x8*)&PB[bbase + (n + 2) * 1024 + swz0];
      b1[n][1] = *(const bf16x8*)&PB[bbase + (n + 2) * 1024 + swz1];
    }
    STAGE(&S[bn][1][8192], pB1, k1);
    BAR();
    __builtin_amdgcn_s_setprio(1);
    #pragma unroll
    for (int m = 0; m < 4; ++m)
      #pragma unroll
      for (int n = 0; n < 2; ++n) {
        acc[m][n + 2] = __builtin_amdgcn_mfma_f32_16x16x32_bf16(a[m][0], b1[n][0], acc[m][n + 2], 0, 0, 0);
        acc[m][n + 2] = __builtin_amdgcn_mfma_f32_16x16x32_bf16(a[m][1], b1[n][1], acc[m][n + 2], 0, 0, 0);
      }
    __builtin_amdgcn_s_setprio(0);
    BAR();

    // ---- p3: Q10 (m 4..7, n 0..1) ----
    #pragma unroll
    for (int m = 0; m < 4; ++m) {
      a[m][0] = *(const bf16x8*)&PA[abase + (m + 4) * 1024 + swz0];
      a[m][1] = *(const bf16x8*)&PA[abase + (m + 4) * 1024 + swz1];
    }
    STAGE(&S[b][1][0], pB0, k2);
    BAR();
    __builtin_amdgcn_s_setprio(1);
    #pragma unroll
    for (int m = 0; m < 4; ++m)
      #pragma unroll
      for (int n = 0; n < 2; ++n) {
        acc[m + 4][n] = __builtin_amdgcn_mfma_f32_16x16x32_bf16(a[m][0], b0[n][0], acc[m + 4][n], 0, 0, 0);
        acc[m + 4][n] = __builtin_amdgcn_mfma_f32_16x16x32_bf16(a[m][1], b0[n][1], acc[m + 4][n], 0, 0, 0);
      }
    __builtin_amdgcn_s_setprio(0);
    BAR();

    // ---- p4: Q11 (m 4..7, n 2..3) ----
    STAGE(&S[b][0][0], pA0, k2);
    WAITV4();
    BAR();
    __builtin_amdgcn_s_setprio(1);
    #pragma unroll
    for (int m = 0; m < 4; ++m)
      #pragma unroll
      for (int n = 0; n < 2; ++n) {
        acc[m + 4][n + 2] = __builtin_amdgcn_mfma_f32_16x16x32_bf16(a[m][0], b1[n][0], acc[m + 4][n + 2], 0, 0, 0);
        acc[m + 4][n + 2] = __builtin_amdgcn_mfma_f32_16x16x32_bf16(a[m][1], b1[n][1], acc[m + 4][n + 2], 0, 0, 0);
      }
    __builtin_amdgcn_s_setprio(0);
    BAR();
  }

  // ---- epilogue: masked exp accumulation (same mapping as validated R1) ----
  const int cgrp = lane >> 4;   // row sub-offset group
  const int c15  = lane & 15;   // col within fragment
  float rp[8][4];
  float cp[4];
  #pragma unroll
  for (int m = 0; m < 8; m++)
    #pragma unroll
    for (int r = 0; r < 4; r++) rp[m][r] = 0.f;
  #pragma unroll
  for (int n = 0; n < 4; n++) cp[n] = 0.f;

  #pragma unroll
  for (int n = 0; n < 4; n++) {
    const int ct   = wn * 64 + n * 16 + c15;
    const int gcol = bcol + ct;
    const float dc = dcol[ct];
    #pragma unroll
    for (int m = 0; m < 8; m++) {
      #pragma unroll
      for (int r = 0; r < 4; r++) {
        const int rt   = wm * 128 + m * 16 + cgrp * 4 + r;
        const int grow = brow + rt;
        const float s  = acc[m][n][r];
        const float e  = __expf(BETA * (s - BASE));
        const float dr = drow[rt];
        const bool off = (grow != gcol);
        if (off && (s + MARGIN > dr)) rp[m][r] += e;
        if (off && (s + MARGIN > dc)) cp[n] += e;
      }
    }
  }
  #pragma unroll
  for (int m = 0; m < 8; m++) {
    #pragma unroll
    for (int r = 0; r < 4; r++) {
      float v = rp[m][r];
      v += __shfl_xor(v, 1); v += __shfl_xor(v, 2);
      v += __shfl_xor(v, 4); v += __shfl_xor(v, 8);
      if (c15 == 0) {
        const int rt = wm * 128 + m * 16 + cgrp * 4 + r;
        atomicAdd(&row_sum[brow + rt], v);
      }
    }
  }
  #pragma unroll
  for (int n = 0; n < 4; n++) {
    float v = cp[n];
    v += __shfl_xor(v, 16); v += __shfl_xor(v, 32);
    if (cgrp == 0) {
      const int ct = wn * 64 + n * 16 + c15;
      atomicAdd(&col_sum[bcol + ct], v);
    }
  }
  #undef STAGE
}

// --------------------------------------------------------------------------
// K3: final scalar reduction
__global__ __launch_bounds__(1024) void finalize_kernel(
    const float* __restrict__ diag, const float* __restrict__ row_sum,
    const float* __restrict__ col_sum, float* __restrict__ out)
{
  const int tid = threadIdx.x;
  float sp = 0.f, sr = 0.f, sc = 0.f;
  for (int i = tid; i < NB; i += 1024) {
    const float pos = diag[i];
    const float x = -ALPHA * (pos - BASE);
    sp += (fmaxf(x, 0.f) + log1pf(__expf(-fabsf(x)))) / ALPHA;
    sr += log1pf(row_sum[i]);
    sc += log1pf(col_sum[i]);
  }
  #pragma unroll
  for (int m = 1; m < 64; m <<= 1) {
    sp += __shfl_xor(sp, m);
    sr += __shfl_xor(sr, m);
    sc += __shfl_xor(sc, m);
  }
  __shared__ float red[3][16];
  const int wid = tid >> 6, lane = tid & 63;
  if (lane == 0) { red[0][wid] = sp; red[1][wid] = sr; red[2][wid] = sc; }
  __syncthreads();
  if (tid == 0) {
    sp = 0.f; sr = 0.f; sc = 0.f;
    #pragma unroll
    for (int w = 0; w < 16; w++) { sp += red[0][w]; sr += red[1][w]; sc += red[2][w]; }
    out[0] = sp / (float)NB + (sr + sc) / (2.f * BETA * (float)NB);
  }
}

// --------------------------------------------------------------------------
extern "C" void kernel_launch(void* const* d_in, const int* in_sizes, int n_in,
                              void* d_out, int out_size, void* d_ws, size_t ws_size,
                              hipStream_t stream) {
  const float* f1 = (const float*)d_in[0];
  const float* f2 = (const float*)d_in[1];
  float* out = (float*)d_out;

  char* ws = (char*)d_ws;
  unsigned short* f1n = (unsigned short*)ws;                               // 16 MB
  unsigned short* f2n = (unsigned short*)(ws + (size_t)16 * 1024 * 1024);  // 16 MB
  float* diag    = (float*)(ws + (size_t)32 * 1024 * 1024);                // 32 KB
  float* row_sum = diag + NB;                                              // 32 KB
  float* col_sum = row_sum + NB;                                           // 32 KB

  norm_diag_kernel<<<NB, 256, 0, stream>>>(f1, f2, f1n, f2n, diag, row_sum, col_sum);

  dim3 grid(NB / 256, NB / 256);
  simloss_gemm_kernel<<<grid, 512, 0, stream>>>(f1n, f2n, diag, row_sum, col_sum);

  finalize_kernel<<<1, 1024, 0, stream>>>(diag, row_sum, col_sum, out);
}

// Round 9
// 272.985 us; speedup vs baseline: 1.4601x; 1.1797x over previous
//
#include <hip/hip_runtime.h>
#include <hip/hip_bf16.h>

#define ALPHA 2.0f
#define BETA 50.0f
#define BASE 0.5f
#define MARGIN 0.1f

constexpr int NB = 8192;   // batch
constexpr int ND = 1024;   // dim
constexpr int BK = 64;     // K-tile
constexpr int NT = ND / BK; // 16 K-tiles (power of 2 -> wrap with &15)

typedef __attribute__((ext_vector_type(8))) short bf16x8;
typedef __attribute__((ext_vector_type(4))) float f32x4;

#define GLOAD_LDS16(g, l) \
  __builtin_amdgcn_global_load_lds((const __attribute__((address_space(1))) void*)(g), \
                                   (__attribute__((address_space(3))) void*)(l), 16, 0, 0)
// Template-faithful: builtin barrier (NO memory-clobber asm -> no
// conservative vmcnt drain), counted vmcnt via asm.
#define BAR()    __builtin_amdgcn_s_barrier()
#define WAITV4() asm volatile("s_waitcnt vmcnt(4)" ::: "memory")

static __device__ inline unsigned short f2bf(float x) {
  unsigned int u = __float_as_uint(x);
  unsigned int r = u + 0x7FFFu + ((u >> 16) & 1u);
  return (unsigned short)(r >> 16);
}

// --------------------------------------------------------------------------
// K1: row-normalize f1,f2 -> bf16; diag[i] = dot(f1n_i, f2n_i); zero sums.
__global__ __launch_bounds__(256) void norm_diag_kernel(
    const float* __restrict__ f1, const float* __restrict__ f2,
    unsigned short* __restrict__ f1n, unsigned short* __restrict__ f2n,
    float* __restrict__ diag, float* __restrict__ row_sum,
    float* __restrict__ col_sum)
{
  const int row = blockIdx.x;
  const int tid = threadIdx.x;
  const float4* r1 = (const float4*)(f1 + (size_t)row * ND);
  const float4* r2 = (const float4*)(f2 + (size_t)row * ND);
  float4 a = r1[tid];
  float4 b = r2[tid];
  float ss1 = a.x*a.x + a.y*a.y + a.z*a.z + a.w*a.w;
  float ss2 = b.x*b.x + b.y*b.y + b.z*b.z + b.w*b.w;
  float d12 = a.x*b.x + a.y*b.y + a.z*b.z + a.w*b.w;
  #pragma unroll
  for (int m = 1; m < 64; m <<= 1) {
    ss1 += __shfl_xor(ss1, m);
    ss2 += __shfl_xor(ss2, m);
    d12 += __shfl_xor(d12, m);
  }
  __shared__ float red[3][4];
  const int wid = tid >> 6, lane = tid & 63;
  if (lane == 0) { red[0][wid] = ss1; red[1][wid] = ss2; red[2][wid] = d12; }
  __syncthreads();
  ss1 = red[0][0] + red[0][1] + red[0][2] + red[0][3];
  ss2 = red[1][0] + red[1][1] + red[1][2] + red[1][3];
  d12 = red[2][0] + red[2][1] + red[2][2] + red[2][3];
  const float rn1 = rsqrtf(ss1);
  const float rn2 = rsqrtf(ss2);
  if (tid == 0) diag[row] = d12 * rn1 * rn2;
  if (tid == 1) row_sum[row] = 0.f;
  if (tid == 2) col_sum[row] = 0.f;
  ushort4 o1, o2;
  o1.x = f2bf(a.x * rn1); o1.y = f2bf(a.y * rn1);
  o1.z = f2bf(a.z * rn1); o1.w = f2bf(a.w * rn1);
  o2.x = f2bf(b.x * rn2); o2.y = f2bf(b.y * rn2);
  o2.z = f2bf(b.z * rn2); o2.w = f2bf(b.w * rn2);
  ((ushort4*)f1n)[(size_t)row * 256 + tid] = o1;
  ((ushort4*)f2n)[(size_t)row * 256 + tid] = o2;
}

// --------------------------------------------------------------------------
// K2: 256x256-tile, 8-wave, phase-scheduled bf16 MFMA GEMM with fused
// MS-loss epilogue. T2 XOR-swizzled LDS; counted vmcnt(4) once per K-tile
// (T4); builtin s_barrier (no drain); setprio (T5); T1 bijective XCD swizzle.
//
// Region read ledger per window t (b=t&1, bn=b^1; all ds_reads from S[b]):
//   A0 read p1+p3 (wm=0) | A1 read p1+p3 (wm=1)
//   B0 read p1+p2 (wn=0,1) | B1 read p1+p2 (wn=2,3)
// Stage placement (issue >=1 barrier after target region's last read):
//   p1: A1(t+1)->S[bn] | p2: B1(t+1)->S[bn] | p3: B0(t+2)->S[b] | p4: A0(t+2)->S[b]
// Issue order A1,B1,B0,A0 => vmcnt(4) at p4 completes all of tile t+1,
// leaving the 4 loads of {B0,A0}(t+2) in flight.
__global__ __launch_bounds__(512, 2) void simloss_gemm_kernel(
    const unsigned short* __restrict__ f1n, const unsigned short* __restrict__ f2n,
    const float* __restrict__ diag,
    float* __restrict__ row_sum, float* __restrict__ col_sum)
{
  __shared__ unsigned short S[2][2][16384];  // [dbuf][A/B][256 rows x 64 cols]
  __shared__ float drow[256];
  __shared__ float dcol[256];

  const int tid  = threadIdx.x;
  const int lane = tid & 63;
  const int wid  = tid >> 6;
  const int wm   = wid >> 2;   // 0..1  -> rows [wm*128, +128)
  const int wn   = wid & 3;    // 0..3  -> cols [wn*64, +64)

  // T1: bijective XCD-aware tile assignment (1024 blocks, 8 XCDs).
  // Dispatch b lands on XCD b%8; give that XCD a 32col x 4row slab,
  // iterated column-major: concurrent working set/XCD ~ 4 A-panels (2MB)
  // + 8 B-panels (4MB) instead of 16.5MB.
  const int bidl = blockIdx.y * gridDim.x + blockIdx.x;
  const int xcd  = bidl & 7;
  const int i128 = bidl >> 3;            // 0..127 within XCD
  const int by   = xcd * 4 + (i128 & 3); // 0..31
  const int bx   = i128 >> 2;            // 0..31
  const int brow = by * 256;
  const int bcol = bx * 256;

  if (tid < 256) drow[tid] = diag[brow + tid];
  else           dcol[tid - 256] = diag[bcol + tid - 256];

  // ---- staging constants (2 x 16B per thread per half-tile) ----
  const int c0 = tid, c1 = tid + 512;
  const size_t off0 = (size_t)(c0 >> 3) * ND + (size_t)((((c0 & 7) ^ ((c0 >> 3) & 7))) * 8);
  const size_t off1 = (size_t)(c1 >> 3) * ND + (size_t)((((c1 & 7) ^ ((c1 >> 3) & 7))) * 8);
  const int lo0 = tid * 8, lo1 = tid * 8 + 4096;  // linear LDS dest (shorts)

  const unsigned short* pA0 = f1n + (size_t)brow * ND;
  const unsigned short* pA1 = pA0 + (size_t)128 * ND;
  const unsigned short* pB0 = f2n + (size_t)bcol * ND;
  const unsigned short* pB1 = pB0 + (size_t)128 * ND;

  #define STAGE(ldsbase, g, kk) do { \
    GLOAD_LDS16((g) + off0 + (kk), (ldsbase) + lo0); \
    GLOAD_LDS16((g) + off1 + (kk), (ldsbase) + lo1); } while (0)

  f32x4 acc[8][4];
  #pragma unroll
  for (int m = 0; m < 8; m++)
    #pragma unroll
    for (int n = 0; n < 4; n++)
      acc[m][n] = (f32x4){0.f, 0.f, 0.f, 0.f};

  // ---- fragment read constants ----
  const int hi = lane >> 4, l15 = lane & 15;
  const int x7 = l15 & 7;
  const int swz0 = (hi ^ x7) * 8;        // k-chunk 0 slot (shorts offset)
  const int swz1 = ((hi + 4) ^ x7) * 8;  // k-chunk 1 slot
  const int abase = (wm * 128 + l15) * 64;
  const int bbase = (wn * 64 + l15) * 64;

  // ---- prologue: tile0 fully + A0/B0 of tile1; keep last 4 loads in flight
  STAGE(&S[0][0][0],    pA0, 0);
  STAGE(&S[0][1][0],    pB0, 0);
  STAGE(&S[0][0][8192], pA1, 0);
  STAGE(&S[0][1][8192], pB1, 0);
  STAGE(&S[1][0][0],    pA0, BK);
  STAGE(&S[1][1][0],    pB0, BK);
  WAITV4();
  BAR();

  bf16x8 a[4][2], b0[2][2], b1[2][2];

  for (int t = 0; t < NT; ++t) {
    const int b  = t & 1, bn = b ^ 1;
    const int k1 = ((t + 1) & 15) * BK;   // wraps harmlessly in last windows
    const int k2 = ((t + 2) & 15) * BK;
    const unsigned short* PA = &S[b][0][0];
    const unsigned short* PB = &S[b][1][0];

    // ---- p1: Q00 (m 0..3, n 0..1) ----
    #pragma unroll
    for (int m = 0; m < 4; ++m) {
      a[m][0] = *(const bf16x8*)&PA[abase + m * 1024 + swz0];
      a[m][1] = *(const bf16x8*)&PA[abase + m * 1024 + swz1];
    }
    #pragma unroll
    for (int n = 0; n < 2; ++n) {
      b0[n][0] = *(const bf16x8*)&PB[bbase + n * 1024 + swz0];
      b0[n][1] = *(const bf16x8*)&PB[bbase + n * 1024 + swz1];
    }
    STAGE(&S[bn][0][8192], pA1, k1);
    BAR();
    __builtin_amdgcn_s_setprio(1);
    // k-outer order: same-acc MFMAs are 8 instructions apart (dep relief)
    #pragma unroll
    for (int k = 0; k < 2; ++k)
      #pragma unroll
      for (int m = 0; m < 4; ++m)
        #pragma unroll
        for (int n = 0; n < 2; ++n)
          acc[m][n] = __builtin_amdgcn_mfma_f32_16x16x32_bf16(a[m][k], b0[n][k], acc[m][n], 0, 0, 0);
    __builtin_amdgcn_s_setprio(0);
    BAR();

    // ---- p2: Q01 (m 0..3, n 2..3) ----
    #pragma unroll
    for (int n = 0; n < 2; ++n) {
      b1[n][0] = *(const bf16x8*)&PB[bbase + (n + 2) * 1024 + swz0];
      b1[n][1] = *(const bf16x8*)&PB[bbase + (n + 2) * 1024 + swz1];
    }
    STAGE(&S[bn][1][8192], pB1, k1);
    BAR();
    __builtin_amdgcn_s_setprio(1);
    #pragma unroll
    for (int k = 0; k < 2; ++k)
      #pragma unroll
      for (int m = 0; m < 4; ++m)
        #pragma unroll
        for (int n = 0; n < 2; ++n)
          acc[m][n + 2] = __builtin_amdgcn_mfma_f32_16x16x32_bf16(a[m][k], b1[n][k], acc[m][n + 2], 0, 0, 0);
    __builtin_amdgcn_s_setprio(0);
    BAR();

    // ---- p3: Q10 (m 4..7, n 0..1) ----
    #pragma unroll
    for (int m = 0; m < 4; ++m) {
      a[m][0] = *(const bf16x8*)&PA[abase + (m + 4) * 1024 + swz0];
      a[m][1] = *(const bf16x8*)&PA[abase + (m + 4) * 1024 + swz1];
    }
    STAGE(&S[b][1][0], pB0, k2);
    BAR();
    __builtin_amdgcn_s_setprio(1);
    #pragma unroll
    for (int k = 0; k < 2; ++k)
      #pragma unroll
      for (int m = 0; m < 4; ++m)
        #pragma unroll
        for (int n = 0; n < 2; ++n)
          acc[m + 4][n] = __builtin_amdgcn_mfma_f32_16x16x32_bf16(a[m][k], b0[n][k], acc[m + 4][n], 0, 0, 0);
    __builtin_amdgcn_s_setprio(0);
    BAR();

    // ---- p4: Q11 (m 4..7, n 2..3) ----
    STAGE(&S[b][0][0], pA0, k2);
    WAITV4();
    BAR();
    __builtin_amdgcn_s_setprio(1);
    #pragma unroll
    for (int k = 0; k < 2; ++k)
      #pragma unroll
      for (int m = 0; m < 4; ++m)
        #pragma unroll
        for (int n = 0; n < 2; ++n)
          acc[m + 4][n + 2] = __builtin_amdgcn_mfma_f32_16x16x32_bf16(a[m][k], b1[n][k], acc[m + 4][n + 2], 0, 0, 0);
    __builtin_amdgcn_s_setprio(0);
    BAR();
  }

  // ---- epilogue: masked exp accumulation (same mapping as validated R1) ----
  const int cgrp = lane >> 4;   // row sub-offset group
  const int c15  = lane & 15;   // col within fragment
  float rp[8][4];
  float cp[4];
  #pragma unroll
  for (int m = 0; m < 8; m++)
    #pragma unroll
    for (int r = 0; r < 4; r++) rp[m][r] = 0.f;
  #pragma unroll
  for (int n = 0; n < 4; n++) cp[n] = 0.f;

  #pragma unroll
  for (int n = 0; n < 4; n++) {
    const int ct   = wn * 64 + n * 16 + c15;
    const int gcol = bcol + ct;
    const float dc = dcol[ct];
    #pragma unroll
    for (int m = 0; m < 8; m++) {
      #pragma unroll
      for (int r = 0; r < 4; r++) {
        const int rt   = wm * 128 + m * 16 + cgrp * 4 + r;
        const int grow = brow + rt;
        const float s  = acc[m][n][r];
        const float e  = __expf(BETA * (s - BASE));
        const float dr = drow[rt];
        const bool off = (grow != gcol);
        if (off && (s + MARGIN > dr)) rp[m][r] += e;
        if (off && (s + MARGIN > dc)) cp[n] += e;
      }
    }
  }
  #pragma unroll
  for (int m = 0; m < 8; m++) {
    #pragma unroll
    for (int r = 0; r < 4; r++) {
      float v = rp[m][r];
      v += __shfl_xor(v, 1); v += __shfl_xor(v, 2);
      v += __shfl_xor(v, 4); v += __shfl_xor(v, 8);
      if (c15 == 0) {
        const int rt = wm * 128 + m * 16 + cgrp * 4 + r;
        atomicAdd(&row_sum[brow + rt], v);
      }
    }
  }
  #pragma unroll
  for (int n = 0; n < 4; n++) {
    float v = cp[n];
    v += __shfl_xor(v, 16); v += __shfl_xor(v, 32);
    if (cgrp == 0) {
      const int ct = wn * 64 + n * 16 + c15;
      atomicAdd(&col_sum[bcol + ct], v);
    }
  }
  #undef STAGE
}

// --------------------------------------------------------------------------
// K3: final scalar reduction
__global__ __launch_bounds__(1024) void finalize_kernel(
    const float* __restrict__ diag, const float* __restrict__ row_sum,
    const float* __restrict__ col_sum, float* __restrict__ out)
{
  const int tid = threadIdx.x;
  float sp = 0.f, sr = 0.f, sc = 0.f;
  for (int i = tid; i < NB; i += 1024) {
    const float pos = diag[i];
    const float x = -ALPHA * (pos - BASE);
    sp += (fmaxf(x, 0.f) + log1pf(__expf(-fabsf(x)))) / ALPHA;
    sr += log1pf(row_sum[i]);
    sc += log1pf(col_sum[i]);
  }
  #pragma unroll
  for (int m = 1; m < 64; m <<= 1) {
    sp += __shfl_xor(sp, m);
    sr += __shfl_xor(sr, m);
    sc += __shfl_xor(sc, m);
  }
  __shared__ float red[3][16];
  const int wid = tid >> 6, lane = tid & 63;
  if (lane == 0) { red[0][wid] = sp; red[1][wid] = sr; red[2][wid] = sc; }
  __syncthreads();
  if (tid == 0) {
    sp = 0.f; sr = 0.f; sc = 0.f;
    #pragma unroll
    for (int w = 0; w < 16; w++) { sp += red[0][w]; sr += red[1][w]; sc += red[2][w]; }
    out[0] = sp / (float)NB + (sr + sc) / (2.f * BETA * (float)NB);
  }
}

// --------------------------------------------------------------------------
extern "C" void kernel_launch(void* const* d_in, const int* in_sizes, int n_in,
                              void* d_out, int out_size, void* d_ws, size_t ws_size,
                              hipStream_t stream) {
  const float* f1 = (const float*)d_in[0];
  const float* f2 = (const float*)d_in[1];
  float* out = (float*)d_out;

  char* ws = (char*)d_ws;
  unsigned short* f1n = (unsigned short*)ws;                               // 16 MB
  unsigned short* f2n = (unsigned short*)(ws + (size_t)16 * 1024 * 1024);  // 16 MB
  float* diag    = (float*)(ws + (size_t)32 * 1024 * 1024);                // 32 KB
  float* row_sum = diag + NB;                                              // 32 KB
  float* col_sum = row_sum + NB;                                           // 32 KB

  norm_diag_kernel<<<NB, 256, 0, stream>>>(f1, f2, f1n, f2n, diag, row_sum, col_sum);

  dim3 grid(NB / 256, NB / 256);
  simloss_gemm_kernel<<<grid, 512, 0, stream>>>(f1n, f2n, diag, row_sum, col_sum);

  finalize_kernel<<<1, 1024, 0, stream>>>(diag, row_sum, col_sum, out);
}